// Round 3
// baseline (1321.244 us; speedup 1.0000x reference)
//
#include <hip/hip_runtime.h>
#include <cstdint>
#include <cstddef>

#define NPOINT 1024
#define NSAMPLE 32
#define BATCH 8
#define NPTS 4096
#define DFEAT 64
#define CIN 67
#define C1 64
#define C2 64
#define C3 128
#define BN_EPS 1e-5f

typedef float f32x2 __attribute__((ext_vector_type(2)));

__device__ __forceinline__ f32x2 pk_add(f32x2 a, f32x2 b) {
    f32x2 d;
    asm("v_pk_add_f32 %0, %1, %2" : "=v"(d) : "v"(a), "v"(b));
    return d;
}
__device__ __forceinline__ f32x2 pk_mul(f32x2 a, f32x2 b) {
    f32x2 d;
    asm("v_pk_mul_f32 %0, %1, %2" : "=v"(d) : "v"(a), "v"(b));
    return d;
}

// ---------------------------------------------------------------------------
// FPS: one block per batch, 256 threads (4 waves), 16 points/thread in regs.
// Bit-exact distance math; packed-f32 scan; argmax with first-index tie-break.
// Winner coords carried through the reduction (no dependent LDS re-read).
// ---------------------------------------------------------------------------
__device__ __forceinline__ float wave64_max_bcast(float v) {
    // values must be >= 0 (bound_ctrl zero-fill loses). Result in lane 63.
    int x;
    x = __builtin_amdgcn_update_dpp(0, __float_as_int(v), 0x111, 0xf, 0xf, true);
    v = fmaxf(v, __int_as_float(x));  // row_shr:1
    x = __builtin_amdgcn_update_dpp(0, __float_as_int(v), 0x112, 0xf, 0xf, true);
    v = fmaxf(v, __int_as_float(x));  // row_shr:2
    x = __builtin_amdgcn_update_dpp(0, __float_as_int(v), 0x114, 0xf, 0xf, true);
    v = fmaxf(v, __int_as_float(x));  // row_shr:4
    x = __builtin_amdgcn_update_dpp(0, __float_as_int(v), 0x118, 0xf, 0xf, true);
    v = fmaxf(v, __int_as_float(x));  // row_shr:8
    x = __builtin_amdgcn_update_dpp(0, __float_as_int(v), 0x142, 0xf, 0xf, true);
    v = fmaxf(v, __int_as_float(x));  // row_bcast:15
    x = __builtin_amdgcn_update_dpp(0, __float_as_int(v), 0x143, 0xf, 0xf, true);
    v = fmaxf(v, __int_as_float(x));  // row_bcast:31
    return __int_as_float(__builtin_amdgcn_readlane(__float_as_int(v), 63));
}

__global__ __launch_bounds__(256) void fps_kernel(const float* __restrict__ xyz,
                                                  float* __restrict__ dout) {
    const int b = blockIdx.x;
    const float* xb = xyz + (size_t)b * 3 * NPTS;
    float* ox = dout + (size_t)b * 3 * NPOINT;

    __shared__ unsigned long long keys[2][4];
    __shared__ float4 scoord[2][4];

    const int t = threadIdx.x;
    constexpr int PT = NPTS / 256;  // 16 points/thread, contiguous
    constexpr int G = PT / 2;       // 8 packed groups
    const int base = t * PT;

    f32x2 px2[G], py2[G], pz2[G], dist2[G];
    {
        const float4* fx = (const float4*)(xb + base);
        const float4* fy = (const float4*)(xb + NPTS + base);
        const float4* fz = (const float4*)(xb + 2 * NPTS + base);
#pragma unroll
        for (int q = 0; q < PT / 4; ++q) {
            float4 vx = fx[q], vy = fy[q], vz = fz[q];
            px2[2 * q] = f32x2{vx.x, vx.y};
            px2[2 * q + 1] = f32x2{vx.z, vx.w};
            py2[2 * q] = f32x2{vy.x, vy.y};
            py2[2 * q + 1] = f32x2{vy.z, vy.w};
            pz2[2 * q] = f32x2{vz.x, vz.y};
            pz2[2 * q + 1] = f32x2{vz.z, vz.w};
        }
#pragma unroll
        for (int g = 0; g < G; ++g) dist2[g] = f32x2{1e10f, 1e10f};
    }

    float cx = xb[0], cy = xb[NPTS], cz = xb[2 * NPTS];
    if (t == 0) {
        ox[0] = cx;
        ox[NPOINT] = cy;
        ox[2 * NPOINT] = cz;
    }

    const int wv = t >> 6;
    for (int s = 1; s < NPOINT; ++s) {
        const f32x2 ncx = {-cx, -cx}, ncy = {-cy, -cy}, ncz = {-cz, -cz};
        float bv = 0.0f;
#pragma unroll
        for (int g = 0; g < G; ++g) {
            f32x2 dx = pk_add(px2[g], ncx);   // == px - cx (IEEE exact)
            f32x2 dy = pk_add(py2[g], ncy);
            f32x2 dz = pk_add(pz2[g], ncz);
            f32x2 xx = pk_mul(dx, dx);
            f32x2 yy = pk_mul(dy, dy);
            f32x2 zz = pk_mul(dz, dz);
            f32x2 sm = pk_add(xx, yy);
            f32x2 d2 = pk_add(sm, zz);
            float n0 = fminf(dist2[g].x, d2.x);
            float n1 = fminf(dist2[g].y, d2.y);
            dist2[g].x = n0;
            dist2[g].y = n1;
            bv = fmaxf(fmaxf(bv, n0), n1);  // -> v_max3
        }
        const float wmax = wave64_max_bcast(bv);

        int li = 0;
        float ccx = 0.f, ccy = 0.f, ccz = 0.f;
        if (bv == wmax) {
#pragma unroll
            for (int g = G - 1; g >= 0; --g) {  // descending -> keeps smallest idx
                if (dist2[g].y == wmax) {
                    li = base + 2 * g + 1;
                    ccx = px2[g].y; ccy = py2[g].y; ccz = pz2[g].y;
                }
                if (dist2[g].x == wmax) {
                    li = base + 2 * g;
                    ccx = px2[g].x; ccy = py2[g].x; ccz = pz2[g].x;
                }
            }
        }
        const unsigned long long m = __ballot(bv == wmax);
        const int fl = __builtin_ctzll(m);  // first lane = smallest indices
        const int wbi = __builtin_amdgcn_readlane(li, fl);
        const float wcx = __int_as_float(__builtin_amdgcn_readlane(__float_as_int(ccx), fl));
        const float wcy = __int_as_float(__builtin_amdgcn_readlane(__float_as_int(ccy), fl));
        const float wcz = __int_as_float(__builtin_amdgcn_readlane(__float_as_int(ccz), fl));

        if ((t & 63) == 0) {
            keys[s & 1][wv] = ((unsigned long long)__float_as_uint(wmax) << 32) |
                              (unsigned)(0xFFFFFFFFu - (unsigned)wbi);
            scoord[s & 1][wv] = make_float4(wcx, wcy, wcz, 0.f);
        }
        __syncthreads();
        unsigned long long gk = keys[s & 1][0];
        float4 gc = scoord[s & 1][0];
#pragma unroll
        for (int w = 1; w < 4; ++w) {
            unsigned long long k2 = keys[s & 1][w];
            float4 c2 = scoord[s & 1][w];
            if (k2 > gk) { gk = k2; gc = c2; }
        }
        cx = gc.x; cy = gc.y; cz = gc.z;
        if (t == 0) {
            ox[s] = cx;
            ox[NPOINT + s] = cy;
            ox[2 * NPOINT + s] = cz;
        }
    }
}

// ---------------------------------------------------------------------------
// Transpose points (B,64,N) -> (B,N,64) so MLP gathers are contiguous.
// ---------------------------------------------------------------------------
__global__ __launch_bounds__(256) void transpose_pts(const float* __restrict__ pts,
                                                     float* __restrict__ ptsT) {
    __shared__ float tile[64][65];
    const int b = blockIdx.x / (NPTS / 64);
    const int n0 = (blockIdx.x % (NPTS / 64)) * 64;
    const int t = threadIdx.x;
    const int nl = t & 63, cq = t >> 6;
    const float* pb = pts + (size_t)b * DFEAT * NPTS;
#pragma unroll
    for (int i = 0; i < 16; ++i) {
        int c = i * 4 + cq;
        tile[c][nl] = pb[(size_t)c * NPTS + n0 + nl];
    }
    __syncthreads();
    float* ob = ptsT + (size_t)b * NPTS * DFEAT;
    const int cl = t & 63, nq = t >> 6;
#pragma unroll
    for (int i = 0; i < 16; ++i) {
        int n = i * 4 + nq;
        ob[(size_t)(n0 + n) * DFEAT + cl] = tile[cl][n];
    }
}

// ---------------------------------------------------------------------------
// Ball query: one wave per query point. First 32 ascending indices with
// d2 <= r2, padded with the first. Bit-exact d2.
// ---------------------------------------------------------------------------
__global__ __launch_bounds__(256) void ballquery_kernel(const float* __restrict__ xyz,
                                                        const float* __restrict__ dout,
                                                        int* __restrict__ idx) {
    const int wv = threadIdx.x >> 6, lane = threadIdx.x & 63;
    const int sg = blockIdx.x * 4 + wv;  // b*NPOINT + s
    const int b = sg / NPOINT, s = sg % NPOINT;
    const float* xb = xyz + (size_t)b * 3 * NPTS;
    const float* nx = dout + (size_t)b * 3 * NPOINT;
    const float cx = nx[s], cy = nx[NPOINT + s], cz = nx[2 * NPOINT + s];
    int* ob = idx + (size_t)sg * NSAMPLE;
    const float r2 = 0.04f;  // f32(0.2*0.2)

    int cnt = 0;
    int first = -1;
    for (int tch = 0; tch < NPTS / 64 && cnt < NSAMPLE; ++tch) {
        const int j = tch * 64 + lane;
        float dx = __fsub_rn(cx, xb[j]);
        float dy = __fsub_rn(cy, xb[NPTS + j]);
        float dz = __fsub_rn(cz, xb[2 * NPTS + j]);
        float d2 = __fadd_rn(__fadd_rn(__fmul_rn(dx, dx), __fmul_rn(dy, dy)),
                             __fmul_rn(dz, dz));
        unsigned long long mask = __ballot(d2 <= r2);
        while (mask && cnt < NSAMPLE) {
            int bit = __builtin_ctzll(mask);
            int pj = tch * 64 + bit;
            if (cnt == 0) first = pj;
            if (lane == 0) ob[cnt] = pj;
            cnt++;
            mask &= mask - 1;
        }
    }
    if (lane == 0) {
        for (int r = cnt; r < NSAMPLE; ++r) ob[r] = first;
    }
}

// ---------------------------------------------------------------------------
// Fused group + 3x conv-BN-ReLU + max over nsample.
// Thread = one (s,k) column; 4-way split accumulators for ILP.
// ---------------------------------------------------------------------------
template <int TRANSPOSED>
__global__ __launch_bounds__(256) void mlp_kernel(
    const float* __restrict__ xyz, const float* __restrict__ pts,
    const int* __restrict__ idx, const float* __restrict__ dnew,
    const float* __restrict__ w0, const float* __restrict__ b0,
    const float* __restrict__ g0, const float* __restrict__ bt0,
    const float* __restrict__ rm0, const float* __restrict__ rv0,
    const float* __restrict__ w1, const float* __restrict__ b1,
    const float* __restrict__ g1, const float* __restrict__ bt1,
    const float* __restrict__ rm1, const float* __restrict__ rv1,
    const float* __restrict__ w2, const float* __restrict__ b2,
    const float* __restrict__ g2, const float* __restrict__ bt2,
    const float* __restrict__ rm2, const float* __restrict__ rv2,
    float* __restrict__ outf) {
    __shared__ float ylds[64][256];
    const int t = threadIdx.x;
    const int k = t & 31, sl = t >> 5;
    const int b = blockIdx.x >> 7;
    const int s = (blockIdx.x & 127) * 8 + sl;
    const int p = idx[((size_t)(b * NPOINT + s)) * NSAMPLE + k];

    const float* xb = xyz + (size_t)b * 3 * NPTS;
    const float* nx = dnew + (size_t)b * 3 * NPOINT;

    float x[CIN];
    x[0] = xb[p] - nx[s];
    x[1] = xb[NPTS + p] - nx[NPOINT + s];
    x[2] = xb[2 * NPTS + p] - nx[2 * NPOINT + s];
    if (TRANSPOSED) {
        const float* pb = pts + ((size_t)b * NPTS + p) * DFEAT;
#pragma unroll
        for (int c = 0; c < DFEAT; ++c) x[3 + c] = pb[c];
    } else {
        const float* pb = pts + (size_t)b * DFEAT * NPTS + p;
#pragma unroll
        for (int c = 0; c < DFEAT; ++c) x[3 + c] = pb[(size_t)c * NPTS];
    }

    // layer 1: 67 -> 64
    for (int o = 0; o < C1; ++o) {
        const float* wr = w0 + o * CIN;
        float a0 = 0.f, a1 = 0.f, a2 = 0.f, a3 = 0.f;
#pragma unroll
        for (int c = 0; c < 64; c += 4) {
            a0 = fmaf(wr[c], x[c], a0);
            a1 = fmaf(wr[c + 1], x[c + 1], a1);
            a2 = fmaf(wr[c + 2], x[c + 2], a2);
            a3 = fmaf(wr[c + 3], x[c + 3], a3);
        }
        a0 = fmaf(wr[64], x[64], a0);
        a1 = fmaf(wr[65], x[65], a1);
        a2 = fmaf(wr[66], x[66], a2);
        float acc = (a0 + a1) + (a2 + a3);
        float sc = g0[o] * rsqrtf(rv0[o] + BN_EPS);
        float y = fmaf(sc, acc + b0[o] - rm0[o], bt0[o]);
        ylds[o][t] = fmaxf(y, 0.f);
    }
    __syncthreads();
    float x1[C1];
#pragma unroll
    for (int c = 0; c < C1; ++c) x1[c] = ylds[c][t];
    __syncthreads();

    // layer 2: 64 -> 64
    for (int o = 0; o < C2; ++o) {
        const float* wr = w1 + o * C1;
        float a0 = 0.f, a1 = 0.f, a2 = 0.f, a3 = 0.f;
#pragma unroll
        for (int c = 0; c < C1; c += 4) {
            a0 = fmaf(wr[c], x1[c], a0);
            a1 = fmaf(wr[c + 1], x1[c + 1], a1);
            a2 = fmaf(wr[c + 2], x1[c + 2], a2);
            a3 = fmaf(wr[c + 3], x1[c + 3], a3);
        }
        float acc = (a0 + a1) + (a2 + a3);
        float sc = g1[o] * rsqrtf(rv1[o] + BN_EPS);
        float y = fmaf(sc, acc + b1[o] - rm1[o], bt1[o]);
        ylds[o][t] = fmaxf(y, 0.f);
    }
    __syncthreads();
    float x2[C2];
#pragma unroll
    for (int c = 0; c < C2; ++c) x2[c] = ylds[c][t];

    // layer 3: 64 -> 128, then max over k (32 lanes sharing s)
    float* ob = outf + (size_t)b * C3 * NPOINT;
    for (int o = 0; o < C3; ++o) {
        const float* wr = w2 + o * C2;
        float a0 = 0.f, a1 = 0.f, a2 = 0.f, a3 = 0.f;
#pragma unroll
        for (int c = 0; c < C2; c += 4) {
            a0 = fmaf(wr[c], x2[c], a0);
            a1 = fmaf(wr[c + 1], x2[c + 1], a1);
            a2 = fmaf(wr[c + 2], x2[c + 2], a2);
            a3 = fmaf(wr[c + 3], x2[c + 3], a3);
        }
        float acc = (a0 + a1) + (a2 + a3);
        float sc = g2[o] * rsqrtf(rv2[o] + BN_EPS);
        float y = fmaf(sc, acc + b2[o] - rm2[o], bt2[o]);
        float v = fmaxf(y, 0.f);
#pragma unroll
        for (int m = 16; m >= 1; m >>= 1) v = fmaxf(v, __shfl_xor(v, m, 32));
        if (k == 0) ob[(size_t)o * NPOINT + s] = v;
    }
}

// ---------------------------------------------------------------------------
extern "C" void kernel_launch(void* const* d_in, const int* in_sizes, int n_in,
                              void* d_out, int out_size, void* d_ws, size_t ws_size,
                              hipStream_t stream) {
    const float* xyz = (const float*)d_in[0];
    const float* pts = (const float*)d_in[1];
    const float* w0 = (const float*)d_in[2];
    const float* b0 = (const float*)d_in[3];
    const float* g0 = (const float*)d_in[4];
    const float* bt0 = (const float*)d_in[5];
    const float* rm0 = (const float*)d_in[6];
    const float* rv0 = (const float*)d_in[7];
    const float* w1 = (const float*)d_in[8];
    const float* b1 = (const float*)d_in[9];
    const float* g1 = (const float*)d_in[10];
    const float* bt1 = (const float*)d_in[11];
    const float* rm1 = (const float*)d_in[12];
    const float* rv1 = (const float*)d_in[13];
    const float* w2 = (const float*)d_in[14];
    const float* b2 = (const float*)d_in[15];
    const float* g2 = (const float*)d_in[16];
    const float* bt2 = (const float*)d_in[17];
    const float* rm2 = (const float*)d_in[18];
    const float* rv2 = (const float*)d_in[19];

    float* out = (float*)d_out;
    float* outf = out + (size_t)BATCH * 3 * NPOINT;

    const size_t idx_bytes = (size_t)BATCH * NPOINT * NSAMPLE * sizeof(int);  // 1 MB
    const size_t idx_pad = (idx_bytes + 255) & ~(size_t)255;
    const size_t ptsT_bytes = (size_t)BATCH * NPTS * DFEAT * sizeof(float);   // 8 MB
    int* idx = (int*)d_ws;
    float* ptsT = (float*)((char*)d_ws + idx_pad);
    const bool useT = ws_size >= idx_pad + ptsT_bytes;

    fps_kernel<<<BATCH, 256, 0, stream>>>(xyz, out);
    if (useT) transpose_pts<<<BATCH * (NPTS / 64), 256, 0, stream>>>(pts, ptsT);
    ballquery_kernel<<<BATCH * NPOINT / 4, 256, 0, stream>>>(xyz, out, idx);
    if (useT) {
        mlp_kernel<1><<<BATCH * NPOINT / 8, 256, 0, stream>>>(
            xyz, ptsT, idx, out, w0, b0, g0, bt0, rm0, rv0, w1, b1, g1, bt1, rm1,
            rv1, w2, b2, g2, bt2, rm2, rv2, outf);
    } else {
        mlp_kernel<0><<<BATCH * NPOINT / 8, 256, 0, stream>>>(
            xyz, pts, idx, out, w0, b0, g0, bt0, rm0, rv0, w1, b1, g1, bt1, rm1,
            rv1, w2, b2, g2, bt2, rm2, rv2, outf);
    }
}

// Round 4
// 1235.855 us; speedup vs baseline: 1.0691x; 1.0691x over previous
//
#include <hip/hip_runtime.h>
#include <cstdint>
#include <cstddef>

#define NPOINT 1024
#define NSAMPLE 32
#define BATCH 8
#define NPTS 4096
#define DFEAT 64
#define CIN 67
#define C1 64
#define C2 64
#define C3 128
#define BN_EPS 1e-5f

typedef float f32x2 __attribute__((ext_vector_type(2)));

__device__ __forceinline__ f32x2 pk_add(f32x2 a, f32x2 b) {
    f32x2 d;
    asm("v_pk_add_f32 %0, %1, %2" : "=v"(d) : "v"(a), "v"(b));
    return d;
}
__device__ __forceinline__ f32x2 pk_mul(f32x2 a, f32x2 b) {
    f32x2 d;
    asm("v_pk_mul_f32 %0, %1, %2" : "=v"(d) : "v"(a), "v"(b));
    return d;
}

// ---------------------------------------------------------------------------
// FPS: one block per batch, 512 threads (8 waves, 2/SIMD for latency hiding),
// 8 points/thread in registers (4 packed f32x2 groups).
// Bit-exact distance math; argmax with first-index tie-break.
// Winning lane writes key+coords straight to LDS (no readlane chain);
// depth-3 tree reduce over the 8 wave entries.
// ---------------------------------------------------------------------------
__device__ __forceinline__ float wave64_max_bcast(float v) {
    // values must be >= 0 (bound_ctrl zero-fill loses). Result in lane 63.
    int x;
    x = __builtin_amdgcn_update_dpp(0, __float_as_int(v), 0x111, 0xf, 0xf, true);
    v = fmaxf(v, __int_as_float(x));  // row_shr:1
    x = __builtin_amdgcn_update_dpp(0, __float_as_int(v), 0x112, 0xf, 0xf, true);
    v = fmaxf(v, __int_as_float(x));  // row_shr:2
    x = __builtin_amdgcn_update_dpp(0, __float_as_int(v), 0x114, 0xf, 0xf, true);
    v = fmaxf(v, __int_as_float(x));  // row_shr:4
    x = __builtin_amdgcn_update_dpp(0, __float_as_int(v), 0x118, 0xf, 0xf, true);
    v = fmaxf(v, __int_as_float(x));  // row_shr:8
    x = __builtin_amdgcn_update_dpp(0, __float_as_int(v), 0x142, 0xf, 0xf, true);
    v = fmaxf(v, __int_as_float(x));  // row_bcast:15
    x = __builtin_amdgcn_update_dpp(0, __float_as_int(v), 0x143, 0xf, 0xf, true);
    v = fmaxf(v, __int_as_float(x));  // row_bcast:31
    return __int_as_float(__builtin_amdgcn_readlane(__float_as_int(v), 63));
}

__global__ __launch_bounds__(512) void fps_kernel(const float* __restrict__ xyz,
                                                  float* __restrict__ dout) {
    const int b = blockIdx.x;
    const float* xb = xyz + (size_t)b * 3 * NPTS;
    float* ox = dout + (size_t)b * 3 * NPOINT;

    __shared__ unsigned long long keys[2][8];
    __shared__ float4 scoord[2][8];

    const int t = threadIdx.x;
    const int wv = t >> 6, lane = t & 63;
    constexpr int PT = NPTS / 512;  // 8 points/thread, contiguous
    constexpr int G = PT / 2;       // 4 packed groups
    const int base = t * PT;

    f32x2 px2[G], py2[G], pz2[G], dist2[G];
    {
        const float4* fx = (const float4*)(xb + base);
        const float4* fy = (const float4*)(xb + NPTS + base);
        const float4* fz = (const float4*)(xb + 2 * NPTS + base);
#pragma unroll
        for (int q = 0; q < PT / 4; ++q) {
            float4 vx = fx[q], vy = fy[q], vz = fz[q];
            px2[2 * q] = f32x2{vx.x, vx.y};
            px2[2 * q + 1] = f32x2{vx.z, vx.w};
            py2[2 * q] = f32x2{vy.x, vy.y};
            py2[2 * q + 1] = f32x2{vy.z, vy.w};
            pz2[2 * q] = f32x2{vz.x, vz.y};
            pz2[2 * q + 1] = f32x2{vz.z, vz.w};
        }
#pragma unroll
        for (int g = 0; g < G; ++g) dist2[g] = f32x2{1e10f, 1e10f};
    }

    float cx = xb[0], cy = xb[NPTS], cz = xb[2 * NPTS];
    if (t == 0) {
        ox[0] = cx;
        ox[NPOINT] = cy;
        ox[2 * NPOINT] = cz;
    }

    for (int s = 1; s < NPOINT; ++s) {
        const f32x2 ncx = {-cx, -cx}, ncy = {-cy, -cy}, ncz = {-cz, -cz};
        float bv = 0.0f;
#pragma unroll
        for (int g = 0; g < G; ++g) {
            f32x2 dx = pk_add(px2[g], ncx);   // == px - cx (IEEE exact)
            f32x2 dy = pk_add(py2[g], ncy);
            f32x2 dz = pk_add(pz2[g], ncz);
            f32x2 xx = pk_mul(dx, dx);
            f32x2 yy = pk_mul(dy, dy);
            f32x2 zz = pk_mul(dz, dz);
            f32x2 sm = pk_add(xx, yy);
            f32x2 d2 = pk_add(sm, zz);
            float n0 = fminf(dist2[g].x, d2.x);
            float n1 = fminf(dist2[g].y, d2.y);
            dist2[g].x = n0;
            dist2[g].y = n1;
            bv = fmaxf(fmaxf(bv, n0), n1);  // -> v_max3
        }
        const float wmax = wave64_max_bcast(bv);

        // recover first matching local index + its coords (predicated rescan)
        const bool hit = (bv == wmax);
        int li = 0;
        float ccx = 0.f, ccy = 0.f, ccz = 0.f;
        if (hit) {
#pragma unroll
            for (int g = G - 1; g >= 0; --g) {  // descending -> keeps smallest idx
                if (dist2[g].y == wmax) {
                    li = base + 2 * g + 1;
                    ccx = px2[g].y; ccy = py2[g].y; ccz = pz2[g].y;
                }
                if (dist2[g].x == wmax) {
                    li = base + 2 * g;
                    ccx = px2[g].x; ccy = py2[g].x; ccz = pz2[g].x;
                }
            }
        }
        const unsigned long long m = __ballot(hit);
        const int fl = __builtin_ctzll(m);  // first matching lane = smallest idx
        if (lane == fl) {
            keys[s & 1][wv] = ((unsigned long long)__float_as_uint(wmax) << 32) |
                              (unsigned)(0xFFFFFFFFu - (unsigned)li);
            scoord[s & 1][wv] = make_float4(ccx, ccy, ccz, 0.f);
        }
        __syncthreads();

        // depth-3 tree reduce over 8 wave entries (broadcast LDS reads)
        const unsigned long long* kk = keys[s & 1];
        const float4* cc = scoord[s & 1];
        unsigned long long k0 = kk[0], k1 = kk[1], k2 = kk[2], k3 = kk[3];
        unsigned long long k4 = kk[4], k5 = kk[5], k6 = kk[6], k7 = kk[7];
        float4 c0 = cc[0], c1 = cc[1], c2 = cc[2], c3 = cc[3];
        float4 c4 = cc[4], c5 = cc[5], c6 = cc[6], c7 = cc[7];
        if (k1 > k0) { k0 = k1; c0 = c1; }
        if (k3 > k2) { k2 = k3; c2 = c3; }
        if (k5 > k4) { k4 = k5; c4 = c5; }
        if (k7 > k6) { k6 = k7; c6 = c7; }
        if (k2 > k0) { k0 = k2; c0 = c2; }
        if (k6 > k4) { k4 = k6; c4 = c6; }
        if (k4 > k0) { k0 = k4; c0 = c4; }
        cx = c0.x; cy = c0.y; cz = c0.z;

        if (t == 0) {
            ox[s] = cx;
            ox[NPOINT + s] = cy;
            ox[2 * NPOINT + s] = cz;
        }
    }
}

// ---------------------------------------------------------------------------
// Transpose points (B,64,N) -> (B,N,64) so MLP gathers are contiguous.
// ---------------------------------------------------------------------------
__global__ __launch_bounds__(256) void transpose_pts(const float* __restrict__ pts,
                                                     float* __restrict__ ptsT) {
    __shared__ float tile[64][65];
    const int b = blockIdx.x / (NPTS / 64);
    const int n0 = (blockIdx.x % (NPTS / 64)) * 64;
    const int t = threadIdx.x;
    const int nl = t & 63, cq = t >> 6;
    const float* pb = pts + (size_t)b * DFEAT * NPTS;
#pragma unroll
    for (int i = 0; i < 16; ++i) {
        int c = i * 4 + cq;
        tile[c][nl] = pb[(size_t)c * NPTS + n0 + nl];
    }
    __syncthreads();
    float* ob = ptsT + (size_t)b * NPTS * DFEAT;
    const int cl = t & 63, nq = t >> 6;
#pragma unroll
    for (int i = 0; i < 16; ++i) {
        int n = i * 4 + nq;
        ob[(size_t)(n0 + n) * DFEAT + cl] = tile[cl][n];
    }
}

// ---------------------------------------------------------------------------
// Ball query: one wave per query point. First 32 ascending indices with
// d2 <= r2, padded with the first. Bit-exact d2.
// ---------------------------------------------------------------------------
__global__ __launch_bounds__(256) void ballquery_kernel(const float* __restrict__ xyz,
                                                        const float* __restrict__ dout,
                                                        int* __restrict__ idx) {
    const int wv = threadIdx.x >> 6, lane = threadIdx.x & 63;
    const int sg = blockIdx.x * 4 + wv;  // b*NPOINT + s
    const int b = sg / NPOINT, s = sg % NPOINT;
    const float* xb = xyz + (size_t)b * 3 * NPTS;
    const float* nx = dout + (size_t)b * 3 * NPOINT;
    const float cx = nx[s], cy = nx[NPOINT + s], cz = nx[2 * NPOINT + s];
    int* ob = idx + (size_t)sg * NSAMPLE;
    const float r2 = 0.04f;  // f32(0.2*0.2)

    int cnt = 0;
    int first = -1;
    for (int tch = 0; tch < NPTS / 64 && cnt < NSAMPLE; ++tch) {
        const int j = tch * 64 + lane;
        float dx = __fsub_rn(cx, xb[j]);
        float dy = __fsub_rn(cy, xb[NPTS + j]);
        float dz = __fsub_rn(cz, xb[2 * NPTS + j]);
        float d2 = __fadd_rn(__fadd_rn(__fmul_rn(dx, dx), __fmul_rn(dy, dy)),
                             __fmul_rn(dz, dz));
        unsigned long long mask = __ballot(d2 <= r2);
        while (mask && cnt < NSAMPLE) {
            int bit = __builtin_ctzll(mask);
            int pj = tch * 64 + bit;
            if (cnt == 0) first = pj;
            if (lane == 0) ob[cnt] = pj;
            cnt++;
            mask &= mask - 1;
        }
    }
    if (lane == 0) {
        for (int r = cnt; r < NSAMPLE; ++r) ob[r] = first;
    }
}

// ---------------------------------------------------------------------------
// Fused group + 3x conv-BN-ReLU + max over nsample.
// Thread = one (s,k) column; 4-way split accumulators for ILP.
// ---------------------------------------------------------------------------
template <int TRANSPOSED>
__global__ __launch_bounds__(256) void mlp_kernel(
    const float* __restrict__ xyz, const float* __restrict__ pts,
    const int* __restrict__ idx, const float* __restrict__ dnew,
    const float* __restrict__ w0, const float* __restrict__ b0,
    const float* __restrict__ g0, const float* __restrict__ bt0,
    const float* __restrict__ rm0, const float* __restrict__ rv0,
    const float* __restrict__ w1, const float* __restrict__ b1,
    const float* __restrict__ g1, const float* __restrict__ bt1,
    const float* __restrict__ rm1, const float* __restrict__ rv1,
    const float* __restrict__ w2, const float* __restrict__ b2,
    const float* __restrict__ g2, const float* __restrict__ bt2,
    const float* __restrict__ rm2, const float* __restrict__ rv2,
    float* __restrict__ outf) {
    __shared__ float ylds[64][256];
    const int t = threadIdx.x;
    const int k = t & 31, sl = t >> 5;
    const int b = blockIdx.x >> 7;
    const int s = (blockIdx.x & 127) * 8 + sl;
    const int p = idx[((size_t)(b * NPOINT + s)) * NSAMPLE + k];

    const float* xb = xyz + (size_t)b * 3 * NPTS;
    const float* nx = dnew + (size_t)b * 3 * NPOINT;

    float x[CIN];
    x[0] = xb[p] - nx[s];
    x[1] = xb[NPTS + p] - nx[NPOINT + s];
    x[2] = xb[2 * NPTS + p] - nx[2 * NPOINT + s];
    if (TRANSPOSED) {
        const float* pb = pts + ((size_t)b * NPTS + p) * DFEAT;
#pragma unroll
        for (int c = 0; c < DFEAT; ++c) x[3 + c] = pb[c];
    } else {
        const float* pb = pts + (size_t)b * DFEAT * NPTS + p;
#pragma unroll
        for (int c = 0; c < DFEAT; ++c) x[3 + c] = pb[(size_t)c * NPTS];
    }

    // layer 1: 67 -> 64
    for (int o = 0; o < C1; ++o) {
        const float* wr = w0 + o * CIN;
        float a0 = 0.f, a1 = 0.f, a2 = 0.f, a3 = 0.f;
#pragma unroll
        for (int c = 0; c < 64; c += 4) {
            a0 = fmaf(wr[c], x[c], a0);
            a1 = fmaf(wr[c + 1], x[c + 1], a1);
            a2 = fmaf(wr[c + 2], x[c + 2], a2);
            a3 = fmaf(wr[c + 3], x[c + 3], a3);
        }
        a0 = fmaf(wr[64], x[64], a0);
        a1 = fmaf(wr[65], x[65], a1);
        a2 = fmaf(wr[66], x[66], a2);
        float acc = (a0 + a1) + (a2 + a3);
        float sc = g0[o] * rsqrtf(rv0[o] + BN_EPS);
        float y = fmaf(sc, acc + b0[o] - rm0[o], bt0[o]);
        ylds[o][t] = fmaxf(y, 0.f);
    }
    __syncthreads();
    float x1[C1];
#pragma unroll
    for (int c = 0; c < C1; ++c) x1[c] = ylds[c][t];
    __syncthreads();

    // layer 2: 64 -> 64
    for (int o = 0; o < C2; ++o) {
        const float* wr = w1 + o * C1;
        float a0 = 0.f, a1 = 0.f, a2 = 0.f, a3 = 0.f;
#pragma unroll
        for (int c = 0; c < C1; c += 4) {
            a0 = fmaf(wr[c], x1[c], a0);
            a1 = fmaf(wr[c + 1], x1[c + 1], a1);
            a2 = fmaf(wr[c + 2], x1[c + 2], a2);
            a3 = fmaf(wr[c + 3], x1[c + 3], a3);
        }
        float acc = (a0 + a1) + (a2 + a3);
        float sc = g1[o] * rsqrtf(rv1[o] + BN_EPS);
        float y = fmaf(sc, acc + b1[o] - rm1[o], bt1[o]);
        ylds[o][t] = fmaxf(y, 0.f);
    }
    __syncthreads();
    float x2[C2];
#pragma unroll
    for (int c = 0; c < C2; ++c) x2[c] = ylds[c][t];

    // layer 3: 64 -> 128, then max over k (32 lanes sharing s)
    float* ob = outf + (size_t)b * C3 * NPOINT;
    for (int o = 0; o < C3; ++o) {
        const float* wr = w2 + o * C2;
        float a0 = 0.f, a1 = 0.f, a2 = 0.f, a3 = 0.f;
#pragma unroll
        for (int c = 0; c < C2; c += 4) {
            a0 = fmaf(wr[c], x2[c], a0);
            a1 = fmaf(wr[c + 1], x2[c + 1], a1);
            a2 = fmaf(wr[c + 2], x2[c + 2], a2);
            a3 = fmaf(wr[c + 3], x2[c + 3], a3);
        }
        float acc = (a0 + a1) + (a2 + a3);
        float sc = g2[o] * rsqrtf(rv2[o] + BN_EPS);
        float y = fmaf(sc, acc + b2[o] - rm2[o], bt2[o]);
        float v = fmaxf(y, 0.f);
#pragma unroll
        for (int m = 16; m >= 1; m >>= 1) v = fmaxf(v, __shfl_xor(v, m, 32));
        if (k == 0) ob[(size_t)o * NPOINT + s] = v;
    }
}

// ---------------------------------------------------------------------------
extern "C" void kernel_launch(void* const* d_in, const int* in_sizes, int n_in,
                              void* d_out, int out_size, void* d_ws, size_t ws_size,
                              hipStream_t stream) {
    const float* xyz = (const float*)d_in[0];
    const float* pts = (const float*)d_in[1];
    const float* w0 = (const float*)d_in[2];
    const float* b0 = (const float*)d_in[3];
    const float* g0 = (const float*)d_in[4];
    const float* bt0 = (const float*)d_in[5];
    const float* rm0 = (const float*)d_in[6];
    const float* rv0 = (const float*)d_in[7];
    const float* w1 = (const float*)d_in[8];
    const float* b1 = (const float*)d_in[9];
    const float* g1 = (const float*)d_in[10];
    const float* bt1 = (const float*)d_in[11];
    const float* rm1 = (const float*)d_in[12];
    const float* rv1 = (const float*)d_in[13];
    const float* w2 = (const float*)d_in[14];
    const float* b2 = (const float*)d_in[15];
    const float* g2 = (const float*)d_in[16];
    const float* bt2 = (const float*)d_in[17];
    const float* rm2 = (const float*)d_in[18];
    const float* rv2 = (const float*)d_in[19];

    float* out = (float*)d_out;
    float* outf = out + (size_t)BATCH * 3 * NPOINT;

    const size_t idx_bytes = (size_t)BATCH * NPOINT * NSAMPLE * sizeof(int);  // 1 MB
    const size_t idx_pad = (idx_bytes + 255) & ~(size_t)255;
    const size_t ptsT_bytes = (size_t)BATCH * NPTS * DFEAT * sizeof(float);   // 8 MB
    int* idx = (int*)d_ws;
    float* ptsT = (float*)((char*)d_ws + idx_pad);
    const bool useT = ws_size >= idx_pad + ptsT_bytes;

    fps_kernel<<<BATCH, 512, 0, stream>>>(xyz, out);
    if (useT) transpose_pts<<<BATCH * (NPTS / 64), 256, 0, stream>>>(pts, ptsT);
    ballquery_kernel<<<BATCH * NPOINT / 4, 256, 0, stream>>>(xyz, out, idx);
    if (useT) {
        mlp_kernel<1><<<BATCH * NPOINT / 8, 256, 0, stream>>>(
            xyz, ptsT, idx, out, w0, b0, g0, bt0, rm0, rv0, w1, b1, g1, bt1, rm1,
            rv1, w2, b2, g2, bt2, rm2, rv2, outf);
    } else {
        mlp_kernel<0><<<BATCH * NPOINT / 8, 256, 0, stream>>>(
            xyz, pts, idx, out, w0, b0, g0, bt0, rm0, rv0, w1, b1, g1, bt1, rm1,
            rv1, w2, b2, g2, bt2, rm2, rv2, outf);
    }
}

// Round 5
// 1096.754 us; speedup vs baseline: 1.2047x; 1.1268x over previous
//
#include <hip/hip_runtime.h>
#include <cstdint>
#include <cstddef>

#define NPOINT 1024
#define NSAMPLE 32
#define BATCH 8
#define NPTS 4096
#define DFEAT 64
#define CIN 67
#define C1 64
#define C2 64
#define C3 128
#define BN_EPS 1e-5f

typedef float f32x2 __attribute__((ext_vector_type(2)));

__device__ __forceinline__ f32x2 pk_add(f32x2 a, f32x2 b) {
    f32x2 d;
    asm("v_pk_add_f32 %0, %1, %2" : "=v"(d) : "v"(a), "v"(b));
    return d;
}
__device__ __forceinline__ f32x2 pk_mul(f32x2 a, f32x2 b) {
    f32x2 d;
    asm("v_pk_mul_f32 %0, %1, %2" : "=v"(d) : "v"(a), "v"(b));
    return d;
}

// ---------------------------------------------------------------------------
// FPS: one block per batch, 512 threads (8 waves, 2/SIMD), 8 pts/thread in
// registers (4 packed f32x2 groups). Bit-exact distances; first-index
// tie-break preserved by lane/wave ordering (ballot+ctz). Tail is 1 LDS
// write + 1 LDS read per thread per step.
// ---------------------------------------------------------------------------
__device__ __forceinline__ float wave64_max_bcast(float v) {
    // values must be >= 0 (bound_ctrl zero-fill loses). Result via lane 63.
    int x;
    x = __builtin_amdgcn_update_dpp(0, __float_as_int(v), 0x111, 0xf, 0xf, true);
    v = fmaxf(v, __int_as_float(x));  // row_shr:1
    x = __builtin_amdgcn_update_dpp(0, __float_as_int(v), 0x112, 0xf, 0xf, true);
    v = fmaxf(v, __int_as_float(x));  // row_shr:2
    x = __builtin_amdgcn_update_dpp(0, __float_as_int(v), 0x114, 0xf, 0xf, true);
    v = fmaxf(v, __int_as_float(x));  // row_shr:4
    x = __builtin_amdgcn_update_dpp(0, __float_as_int(v), 0x118, 0xf, 0xf, true);
    v = fmaxf(v, __int_as_float(x));  // row_shr:8
    x = __builtin_amdgcn_update_dpp(0, __float_as_int(v), 0x142, 0xf, 0xf, true);
    v = fmaxf(v, __int_as_float(x));  // row_bcast:15
    x = __builtin_amdgcn_update_dpp(0, __float_as_int(v), 0x143, 0xf, 0xf, true);
    v = fmaxf(v, __int_as_float(x));  // row_bcast:31
    return __int_as_float(__builtin_amdgcn_readlane(__float_as_int(v), 63));
}

__device__ __forceinline__ float row_max8(float v) {
    // max over lanes 0..7 (values replicated with period 8); result in lane 7.
    int x;
    x = __builtin_amdgcn_update_dpp(0, __float_as_int(v), 0x111, 0xf, 0xf, true);
    v = fmaxf(v, __int_as_float(x));  // row_shr:1
    x = __builtin_amdgcn_update_dpp(0, __float_as_int(v), 0x112, 0xf, 0xf, true);
    v = fmaxf(v, __int_as_float(x));  // row_shr:2
    x = __builtin_amdgcn_update_dpp(0, __float_as_int(v), 0x114, 0xf, 0xf, true);
    v = fmaxf(v, __int_as_float(x));  // row_shr:4
    return __int_as_float(__builtin_amdgcn_readlane(__float_as_int(v), 7));
}

__global__ __launch_bounds__(512) void fps_kernel(const float* __restrict__ xyz,
                                                  float* __restrict__ dout) {
    const int b = blockIdx.x;
    const float* xb = xyz + (size_t)b * 3 * NPTS;
    float* ox = dout + (size_t)b * 3 * NPOINT;

    __shared__ float4 swin[2][8];  // {x, y, z, dist} per wave, double-buffered

    const int t = threadIdx.x;
    const int wv = t >> 6, lane = t & 63;
    constexpr int PT = NPTS / 512;  // 8 points/thread, contiguous
    constexpr int G = PT / 2;       // 4 packed groups
    const int base = t * PT;

    f32x2 px2[G], py2[G], pz2[G], dist2[G];
    {
        const float4* fx = (const float4*)(xb + base);
        const float4* fy = (const float4*)(xb + NPTS + base);
        const float4* fz = (const float4*)(xb + 2 * NPTS + base);
#pragma unroll
        for (int q = 0; q < PT / 4; ++q) {
            float4 vx = fx[q], vy = fy[q], vz = fz[q];
            px2[2 * q] = f32x2{vx.x, vx.y};
            px2[2 * q + 1] = f32x2{vx.z, vx.w};
            py2[2 * q] = f32x2{vy.x, vy.y};
            py2[2 * q + 1] = f32x2{vy.z, vy.w};
            pz2[2 * q] = f32x2{vz.x, vz.y};
            pz2[2 * q + 1] = f32x2{vz.z, vz.w};
        }
#pragma unroll
        for (int g = 0; g < G; ++g) dist2[g] = f32x2{1e10f, 1e10f};
    }

    float cx = xb[0], cy = xb[NPTS], cz = xb[2 * NPTS];
    if (t == 0) {
        ox[0] = cx;
        ox[NPOINT] = cy;
        ox[2 * NPOINT] = cz;
    }

    for (int s = 1; s < NPOINT; ++s) {
        const f32x2 ncx = {-cx, -cx}, ncy = {-cy, -cy}, ncz = {-cz, -cz};
        float bv = 0.0f;
#pragma unroll
        for (int g = 0; g < G; ++g) {
            f32x2 dx = pk_add(px2[g], ncx);   // == px - cx (IEEE exact)
            f32x2 dy = pk_add(py2[g], ncy);
            f32x2 dz = pk_add(pz2[g], ncz);
            f32x2 xx = pk_mul(dx, dx);
            f32x2 yy = pk_mul(dy, dy);
            f32x2 zz = pk_mul(dz, dz);
            f32x2 sm = pk_add(xx, yy);
            f32x2 d2 = pk_add(sm, zz);
            float n0 = fminf(dist2[g].x, d2.x);
            float n1 = fminf(dist2[g].y, d2.y);
            dist2[g].x = n0;
            dist2[g].y = n1;
            bv = fmaxf(fmaxf(bv, n0), n1);  // -> v_max3
        }
        const float wmax = wave64_max_bcast(bv);

        // first matching lane (ballot order == ascending point index)
        const bool hit = (bv == wmax);
        const unsigned long long m = __ballot(hit);
        const int fl = __builtin_ctzll(m);

        if (lane == fl) {
            // predicated rescan (only the winning lane): first matching point
            float ccx = 0.f, ccy = 0.f, ccz = 0.f;
#pragma unroll
            for (int g = G - 1; g >= 0; --g) {  // descending -> keeps smallest
                if (dist2[g].y == wmax) { ccx = px2[g].y; ccy = py2[g].y; ccz = pz2[g].y; }
                if (dist2[g].x == wmax) { ccx = px2[g].x; ccy = py2[g].x; ccz = pz2[g].x; }
            }
            swin[s & 1][wv] = make_float4(ccx, ccy, ccz, wmax);
        }
        __syncthreads();

        // cross-wave pick: 1 ds_read_b128/thread, 3-step DPP max, ballot+ctz
        const float4 e = swin[s & 1][lane & 7];
        const float gmax = row_max8(e.w);
        const unsigned long long m2 = __ballot(e.w == gmax);
        const int ws = __builtin_ctzll(m2);  // smallest wave id -> smallest idx
        cx = __int_as_float(__builtin_amdgcn_readlane(__float_as_int(e.x), ws));
        cy = __int_as_float(__builtin_amdgcn_readlane(__float_as_int(e.y), ws));
        cz = __int_as_float(__builtin_amdgcn_readlane(__float_as_int(e.z), ws));

        if (t == 0) {
            ox[s] = cx;
            ox[NPOINT + s] = cy;
            ox[2 * NPOINT + s] = cz;
        }
    }
}

// ---------------------------------------------------------------------------
// Transpose points (B,64,N) -> (B,N,64) so MLP gathers are contiguous.
// ---------------------------------------------------------------------------
__global__ __launch_bounds__(256) void transpose_pts(const float* __restrict__ pts,
                                                     float* __restrict__ ptsT) {
    __shared__ float tile[64][65];
    const int b = blockIdx.x / (NPTS / 64);
    const int n0 = (blockIdx.x % (NPTS / 64)) * 64;
    const int t = threadIdx.x;
    const int nl = t & 63, cq = t >> 6;
    const float* pb = pts + (size_t)b * DFEAT * NPTS;
#pragma unroll
    for (int i = 0; i < 16; ++i) {
        int c = i * 4 + cq;
        tile[c][nl] = pb[(size_t)c * NPTS + n0 + nl];
    }
    __syncthreads();
    float* ob = ptsT + (size_t)b * NPTS * DFEAT;
    const int cl = t & 63, nq = t >> 6;
#pragma unroll
    for (int i = 0; i < 16; ++i) {
        int n = i * 4 + nq;
        ob[(size_t)(n0 + n) * DFEAT + cl] = tile[cl][n];
    }
}

// ---------------------------------------------------------------------------
// Ball query: one wave per query point. First 32 ascending indices with
// d2 <= r2, padded with the first. Bit-exact d2.
// ---------------------------------------------------------------------------
__global__ __launch_bounds__(256) void ballquery_kernel(const float* __restrict__ xyz,
                                                        const float* __restrict__ dout,
                                                        int* __restrict__ idx) {
    const int wv = threadIdx.x >> 6, lane = threadIdx.x & 63;
    const int sg = blockIdx.x * 4 + wv;  // b*NPOINT + s
    const int b = sg / NPOINT, s = sg % NPOINT;
    const float* xb = xyz + (size_t)b * 3 * NPTS;
    const float* nx = dout + (size_t)b * 3 * NPOINT;
    const float cx = nx[s], cy = nx[NPOINT + s], cz = nx[2 * NPOINT + s];
    int* ob = idx + (size_t)sg * NSAMPLE;
    const float r2 = 0.04f;  // f32(0.2*0.2)

    int cnt = 0;
    int first = -1;
    for (int tch = 0; tch < NPTS / 64 && cnt < NSAMPLE; ++tch) {
        const int j = tch * 64 + lane;
        float dx = __fsub_rn(cx, xb[j]);
        float dy = __fsub_rn(cy, xb[NPTS + j]);
        float dz = __fsub_rn(cz, xb[2 * NPTS + j]);
        float d2 = __fadd_rn(__fadd_rn(__fmul_rn(dx, dx), __fmul_rn(dy, dy)),
                             __fmul_rn(dz, dz));
        unsigned long long mask = __ballot(d2 <= r2);
        while (mask && cnt < NSAMPLE) {
            int bit = __builtin_ctzll(mask);
            int pj = tch * 64 + bit;
            if (cnt == 0) first = pj;
            if (lane == 0) ob[cnt] = pj;
            cnt++;
            mask &= mask - 1;
        }
    }
    if (lane == 0) {
        for (int r = cnt; r < NSAMPLE; ++r) ob[r] = first;
    }
}

// ---------------------------------------------------------------------------
// Fused group + 3x conv-BN-ReLU + max over nsample.
// Thread = one (s,k) column; 4-way split accumulators for ILP.
// ---------------------------------------------------------------------------
template <int TRANSPOSED>
__global__ __launch_bounds__(256) void mlp_kernel(
    const float* __restrict__ xyz, const float* __restrict__ pts,
    const int* __restrict__ idx, const float* __restrict__ dnew,
    const float* __restrict__ w0, const float* __restrict__ b0,
    const float* __restrict__ g0, const float* __restrict__ bt0,
    const float* __restrict__ rm0, const float* __restrict__ rv0,
    const float* __restrict__ w1, const float* __restrict__ b1,
    const float* __restrict__ g1, const float* __restrict__ bt1,
    const float* __restrict__ rm1, const float* __restrict__ rv1,
    const float* __restrict__ w2, const float* __restrict__ b2,
    const float* __restrict__ g2, const float* __restrict__ bt2,
    const float* __restrict__ rm2, const float* __restrict__ rv2,
    float* __restrict__ outf) {
    __shared__ float ylds[64][256];
    const int t = threadIdx.x;
    const int k = t & 31, sl = t >> 5;
    const int b = blockIdx.x >> 7;
    const int s = (blockIdx.x & 127) * 8 + sl;
    const int p = idx[((size_t)(b * NPOINT + s)) * NSAMPLE + k];

    const float* xb = xyz + (size_t)b * 3 * NPTS;
    const float* nx = dnew + (size_t)b * 3 * NPOINT;

    float x[CIN];
    x[0] = xb[p] - nx[s];
    x[1] = xb[NPTS + p] - nx[NPOINT + s];
    x[2] = xb[2 * NPTS + p] - nx[2 * NPOINT + s];
    if (TRANSPOSED) {
        const float* pb = pts + ((size_t)b * NPTS + p) * DFEAT;
#pragma unroll
        for (int c = 0; c < DFEAT; ++c) x[3 + c] = pb[c];
    } else {
        const float* pb = pts + (size_t)b * DFEAT * NPTS + p;
#pragma unroll
        for (int c = 0; c < DFEAT; ++c) x[3 + c] = pb[(size_t)c * NPTS];
    }

    // layer 1: 67 -> 64
    for (int o = 0; o < C1; ++o) {
        const float* wr = w0 + o * CIN;
        float a0 = 0.f, a1 = 0.f, a2 = 0.f, a3 = 0.f;
#pragma unroll
        for (int c = 0; c < 64; c += 4) {
            a0 = fmaf(wr[c], x[c], a0);
            a1 = fmaf(wr[c + 1], x[c + 1], a1);
            a2 = fmaf(wr[c + 2], x[c + 2], a2);
            a3 = fmaf(wr[c + 3], x[c + 3], a3);
        }
        a0 = fmaf(wr[64], x[64], a0);
        a1 = fmaf(wr[65], x[65], a1);
        a2 = fmaf(wr[66], x[66], a2);
        float acc = (a0 + a1) + (a2 + a3);
        float sc = g0[o] * rsqrtf(rv0[o] + BN_EPS);
        float y = fmaf(sc, acc + b0[o] - rm0[o], bt0[o]);
        ylds[o][t] = fmaxf(y, 0.f);
    }
    __syncthreads();
    float x1[C1];
#pragma unroll
    for (int c = 0; c < C1; ++c) x1[c] = ylds[c][t];
    __syncthreads();

    // layer 2: 64 -> 64
    for (int o = 0; o < C2; ++o) {
        const float* wr = w1 + o * C1;
        float a0 = 0.f, a1 = 0.f, a2 = 0.f, a3 = 0.f;
#pragma unroll
        for (int c = 0; c < C1; c += 4) {
            a0 = fmaf(wr[c], x1[c], a0);
            a1 = fmaf(wr[c + 1], x1[c + 1], a1);
            a2 = fmaf(wr[c + 2], x1[c + 2], a2);
            a3 = fmaf(wr[c + 3], x1[c + 3], a3);
        }
        float acc = (a0 + a1) + (a2 + a3);
        float sc = g1[o] * rsqrtf(rv1[o] + BN_EPS);
        float y = fmaf(sc, acc + b1[o] - rm1[o], bt1[o]);
        ylds[o][t] = fmaxf(y, 0.f);
    }
    __syncthreads();
    float x2[C2];
#pragma unroll
    for (int c = 0; c < C2; ++c) x2[c] = ylds[c][t];

    // layer 3: 64 -> 128, then max over k (32 lanes sharing s)
    float* ob = outf + (size_t)b * C3 * NPOINT;
    for (int o = 0; o < C3; ++o) {
        const float* wr = w2 + o * C2;
        float a0 = 0.f, a1 = 0.f, a2 = 0.f, a3 = 0.f;
#pragma unroll
        for (int c = 0; c < C2; c += 4) {
            a0 = fmaf(wr[c], x2[c], a0);
            a1 = fmaf(wr[c + 1], x2[c + 1], a1);
            a2 = fmaf(wr[c + 2], x2[c + 2], a2);
            a3 = fmaf(wr[c + 3], x2[c + 3], a3);
        }
        float acc = (a0 + a1) + (a2 + a3);
        float sc = g2[o] * rsqrtf(rv2[o] + BN_EPS);
        float y = fmaf(sc, acc + b2[o] - rm2[o], bt2[o]);
        float v = fmaxf(y, 0.f);
#pragma unroll
        for (int m = 16; m >= 1; m >>= 1) v = fmaxf(v, __shfl_xor(v, m, 32));
        if (k == 0) ob[(size_t)o * NPOINT + s] = v;
    }
}

// ---------------------------------------------------------------------------
extern "C" void kernel_launch(void* const* d_in, const int* in_sizes, int n_in,
                              void* d_out, int out_size, void* d_ws, size_t ws_size,
                              hipStream_t stream) {
    const float* xyz = (const float*)d_in[0];
    const float* pts = (const float*)d_in[1];
    const float* w0 = (const float*)d_in[2];
    const float* b0 = (const float*)d_in[3];
    const float* g0 = (const float*)d_in[4];
    const float* bt0 = (const float*)d_in[5];
    const float* rm0 = (const float*)d_in[6];
    const float* rv0 = (const float*)d_in[7];
    const float* w1 = (const float*)d_in[8];
    const float* b1 = (const float*)d_in[9];
    const float* g1 = (const float*)d_in[10];
    const float* bt1 = (const float*)d_in[11];
    const float* rm1 = (const float*)d_in[12];
    const float* rv1 = (const float*)d_in[13];
    const float* w2 = (const float*)d_in[14];
    const float* b2 = (const float*)d_in[15];
    const float* g2 = (const float*)d_in[16];
    const float* bt2 = (const float*)d_in[17];
    const float* rm2 = (const float*)d_in[18];
    const float* rv2 = (const float*)d_in[19];

    float* out = (float*)d_out;
    float* outf = out + (size_t)BATCH * 3 * NPOINT;

    const size_t idx_bytes = (size_t)BATCH * NPOINT * NSAMPLE * sizeof(int);  // 1 MB
    const size_t idx_pad = (idx_bytes + 255) & ~(size_t)255;
    const size_t ptsT_bytes = (size_t)BATCH * NPTS * DFEAT * sizeof(float);   // 8 MB
    int* idx = (int*)d_ws;
    float* ptsT = (float*)((char*)d_ws + idx_pad);
    const bool useT = ws_size >= idx_pad + ptsT_bytes;

    fps_kernel<<<BATCH, 512, 0, stream>>>(xyz, out);
    if (useT) transpose_pts<<<BATCH * (NPTS / 64), 256, 0, stream>>>(pts, ptsT);
    ballquery_kernel<<<BATCH * NPOINT / 4, 256, 0, stream>>>(xyz, out, idx);
    if (useT) {
        mlp_kernel<1><<<BATCH * NPOINT / 8, 256, 0, stream>>>(
            xyz, ptsT, idx, out, w0, b0, g0, bt0, rm0, rv0, w1, b1, g1, bt1, rm1,
            rv1, w2, b2, g2, bt2, rm2, rv2, outf);
    } else {
        mlp_kernel<0><<<BATCH * NPOINT / 8, 256, 0, stream>>>(
            xyz, pts, idx, out, w0, b0, g0, bt0, rm0, rv0, w1, b1, g1, bt1, rm1,
            rv1, w2, b2, g2, bt2, rm2, rv2, outf);
    }
}